// Round 7
// baseline (238.704 us; speedup 1.0000x reference)
//
#include <hip/hip_runtime.h>

// Sparsemax, d=1024, 32768 rows, fp32 — 4 rows per wave, 16 lanes/row.
// R0-R6 record: seven variants (ILP, persistent, sched_barrier pipeline,
// two-pass, LDS-DMA prefetch, top-4 compaction) all land 75-84us with
// HBM ~31%, VALU ~30%. Time is invariant to occupancy, prefetch, and
// (mostly) VALU volume; the constant is ONE WAVE-SERIAL SOLVE PER ROW
// (~1400 CU-cyc/row vs ~170 of issue). This round amortizes the solve:
// the wave's 4 sixteen-lane groups each own a row; one instruction
// stream solves 4 rows in lockstep. Group reductions = 4 DPP row_shr
// folds (+1 ds_swizzle broadcast of lane15: offset 0x1F0). No readlane,
// no ballot, no SALU round-trip in the Newton loop; t is per-lane
// (group-uniform). Per-lane top-4-of-64 sorting network feeds exact
// 4-element Newton iterations; if any lane's 4th-largest > max-1
// (ballot, ~4% of waves), the whole wave runs the exact full-64 path.
// Newton t' = t + (S(t)-1)/C(t) from t0 = max-1 is monotone from below
// on the convex piecewise-linear objective (~5-8 iters). rcp not divide
// (C is an exact small int; final step -> 0; tau err ~1e-7 << 2e-3 tol).

#define ROW_D 1024

typedef float f4 __attribute__((ext_vector_type(4)));

template <int CTRL, int RMASK>
__device__ __forceinline__ float dpp_mv(float x) {
    return __builtin_bit_cast(float, __builtin_amdgcn_update_dpp(
        __builtin_bit_cast(int, x), __builtin_bit_cast(int, x),
        CTRL, RMASK, 0xf, false));
}

// Broadcast lane 15 of each 16-lane group to the whole group.
// BitMode swizzle: src = (lane&0x10)|0xF -> offset (0<<10)|(0xF<<5)|0x10.
__device__ __forceinline__ float grp_bcast15(float x) {
    return __builtin_bit_cast(float, __builtin_amdgcn_ds_swizzle(
        __builtin_bit_cast(int, x), 0x1F0));
}

// Group(16-lane) sum/max: fold into lane15 via row_shr (invalid srcs keep
// old value; lane15's accumulation chain only uses valid srcs), then
// broadcast lane15 back to the group.
__device__ __forceinline__ float grp_sum16(float x) {
    x += dpp_mv<0x111, 0xf>(x);   // row_shr:1
    x += dpp_mv<0x112, 0xf>(x);   // row_shr:2
    x += dpp_mv<0x114, 0xf>(x);   // row_shr:4
    x += dpp_mv<0x118, 0xf>(x);   // row_shr:8
    return grp_bcast15(x);
}
__device__ __forceinline__ float grp_max16(float x) {
    x = fmaxf(x, dpp_mv<0x111, 0xf>(x));
    x = fmaxf(x, dpp_mv<0x112, 0xf>(x));
    x = fmaxf(x, dpp_mv<0x114, 0xf>(x));
    x = fmaxf(x, dpp_mv<0x118, 0xf>(x));
    return grp_bcast15(x);
}
__device__ __forceinline__ float fast_rcp(float x) {
    float r;
    asm("v_rcp_f32 %0, %1" : "=v"(r) : "v"(x));
    return r;
}

// Compare-exchange, descending (a keeps max).
__device__ __forceinline__ void ce(float& a, float& b) {
    const float hi = fmaxf(a, b);
    const float lo = fminf(a, b);
    a = hi; b = lo;
}
// Sort 4 desc: 5 CE.
__device__ __forceinline__ void sort4(float& a, float& b, float& c, float& d) {
    ce(a, b); ce(c, d); ce(a, c); ce(b, d); ce(b, c);
}
// Top-4 of two desc-sorted 4-lists (pruned odd-even merge).
__device__ __forceinline__ void merge44_top4(
    float A0, float A1, float A2, float A3,
    float B0, float B1, float B2, float B3,
    float& R0, float& R1, float& R2, float& R3) {
    float e0 = A0, e1 = A2, e2 = B0, e3 = B2;
    ce(e0, e2); ce(e1, e3); ce(e1, e2);
    float o0 = A1, o1 = A3, o2 = B1, o3 = B3;
    ce(o0, o2); ce(o1, o3); ce(o1, o2);
    R0 = e0;
    float x = o0, y = e1;
    ce(x, y);
    R1 = x; R2 = y;
    R3 = fmaxf(o1, e2);
}

__global__ __launch_bounds__(256) void sparsemax_kernel(
    const float* __restrict__ z, float* __restrict__ out, int nrows) {
    const int lane = (int)(threadIdx.x & 63u);
    const int g    = lane >> 4;                       // group 0..3 in wave
    const int p    = lane & 15;                       // pos in group
    const int wid  = (int)(blockIdx.x << 2) + (int)(threadIdx.x >> 6);
    const int row  = (wid << 2) + g;                  // 4 rows per wave
    if (row >= nrows) return;                         // whole-group exit

    const f4* __restrict__ zrow = reinterpret_cast<const f4*>(z + (size_t)row * ROW_D);
    f4* __restrict__ prow       = reinterpret_cast<f4*>(out + (size_t)row * ROW_D);

    // 64 elements/lane: 16 dwordx4 loads; each inst covers 4 x 256B
    // contiguous segments (one per group/row) = 16 lines, same as R0.
    f4 v[16];
#pragma unroll
    for (int j = 0; j < 16; ++j) v[j] = zrow[p + 16 * j];

    // Per-lane top-4 of 64: sort chunk 0, then sort+merge 15 chunks.
    float R0 = v[0].x, R1 = v[0].y, R2 = v[0].z, R3 = v[0].w;
    sort4(R0, R1, R2, R3);
#pragma unroll
    for (int j = 1; j < 16; ++j) {
        float c0 = v[j].x, c1 = v[j].y, c2 = v[j].z, c3 = v[j].w;
        sort4(c0, c1, c2, c3);
        merge44_top4(R0, R1, R2, R3, c0, c1, c2, c3, R0, R1, R2, R3);
    }

    // Row max (group max of lane maxes = R0), group-uniform per lane.
    const float m = grp_max16(R0);
    float t = m - 1.0f;

    // Elements outside a lane's top-4 are <= R3. If R3 <= t0 on every
    // lane, they are <= t for all Newton iterates (t only increases):
    // 4-element iterations are exact. Else whole wave runs full path.
    if (__ballot(R3 > t) == 0ull) {
#pragma unroll 1
        for (int it = 0; it < 16; ++it) {
            const float d0 = R0 - t, d1 = R1 - t, d2 = R2 - t, d3 = R3 - t;
            const float Sl = (fmaxf(d0, 0.0f) + fmaxf(d1, 0.0f)) +
                             (fmaxf(d2, 0.0f) + fmaxf(d3, 0.0f));
            const float Cl = ((d0 > 0.0f ? 1.0f : 0.0f) + (d1 > 0.0f ? 1.0f : 0.0f)) +
                             ((d2 > 0.0f ? 1.0f : 0.0f) + (d3 > 0.0f ? 1.0f : 0.0f));
            const float S = grp_sum16(Sl);     // two independent trees
            const float C = grp_sum16(Cl);     // interleave in the SIMD
            const float step = (S - 1.0f) * fast_rcp(C);   // C >= 1 always
            t += step;
            if (__ballot(step > 1e-6f) == 0ull) break;  // all groups done
        }
    } else {
        // Exact full path (rare): all 64 elements/lane.
#pragma unroll 1
        for (int it = 0; it < 16; ++it) {
            float Sl = 0.0f, Cl = 0.0f;
#pragma unroll
            for (int j = 0; j < 16; ++j) {
                const float d0 = v[j].x - t, d1 = v[j].y - t;
                const float d2 = v[j].z - t, d3 = v[j].w - t;
                Sl += (fmaxf(d0, 0.0f) + fmaxf(d1, 0.0f)) +
                      (fmaxf(d2, 0.0f) + fmaxf(d3, 0.0f));
                Cl += ((d0 > 0.0f ? 1.0f : 0.0f) + (d1 > 0.0f ? 1.0f : 0.0f)) +
                      ((d2 > 0.0f ? 1.0f : 0.0f) + (d3 > 0.0f ? 1.0f : 0.0f));
            }
            const float S = grp_sum16(Sl);
            const float C = grp_sum16(Cl);
            const float step = (S - 1.0f) * fast_rcp(C);
            t += step;
            if (__ballot(step > 1e-6f) == 0ull) break;
        }
    }

    // p = relu(z - tau); t is per-lane (group-uniform).
#pragma unroll
    for (int j = 0; j < 16; ++j) {
        f4 o;
        o.x = fmaxf(v[j].x - t, 0.0f);
        o.y = fmaxf(v[j].y - t, 0.0f);
        o.z = fmaxf(v[j].z - t, 0.0f);
        o.w = fmaxf(v[j].w - t, 0.0f);
        prow[p + 16 * j] = o;
    }
}

extern "C" void kernel_launch(void* const* d_in, const int* in_sizes, int n_in,
                              void* d_out, int out_size, void* d_ws, size_t ws_size,
                              hipStream_t stream) {
    const float* z = (const float*)d_in[0];
    float* out = (float*)d_out;
    const int n = in_sizes[0];            // 8*4096*1024
    const int nrows = n / ROW_D;          // 32768
    // 16 rows per 256-thread block (4 waves x 4 rows).
    const int blocks = (nrows + 15) / 16; // 2048
    sparsemax_kernel<<<blocks, 256, 0, stream>>>(z, out, nrows);
}

// Round 8
// 229.876 us; speedup vs baseline: 1.0384x; 1.0384x over previous
//
#include <hip/hip_runtime.h>

// Sparsemax, d=1024, 32768 rows, fp32 — LOW-CONCURRENCY persistent stream.
// R0-R7 ledger: nine structures, all 75-90us, HBM ~30% + VALU ~30%.
// The >6.5TB/s kernels on this chip (fillBuffer 6.7, float4 copy 6.3) run
// at ~10% occupancy: few waves, continuous issue. Every variant of ours
// ran 2500-5000 waves each bursting 4KB then going silent: 10-32MB of
// demand vs the ~4-6MB BW-latency product -> memory-queue oversubscription,
// inflating wave lifetime to ~12us. This round runs the fillBuffer
// operating point: 512 blocks x 4 waves = 2048 persistent waves (~6%
// occupancy), each pipelining 16 rows via the R5 LDS-DMA prefetch
// (global_load_lds: zero-VGPR, un-sinkable) + R6 top-4 solve.
// Per-iteration vmem order: [solve | DMA next+1 | store cur | vmcnt(8)
// | ds_read next]. DMA precedes stores, and vmcnt retires in issue
// order, so vmcnt(8) drains exactly the prefetch without store-acks.
// Solve: per-lane top-4-of-16 network -> exact 4-elem Newton
//   t' = t + (S(t)-1)/C(t),  t0 = max-1  (monotone from below, ~5-8 it);
// wave falls back to the full 16-elem path if any lane's 4th-largest
// > max-1 (ballot, rare). rcp not divide (exact small-int C; final step
// -> 0; tau err ~1e-7 << 2e-3 tol).

#define ROW_D 1024

typedef float f4 __attribute__((ext_vector_type(4)));

template <int CTRL, int RMASK>
__device__ __forceinline__ float dpp_mv(float x) {
    return __builtin_bit_cast(float, __builtin_amdgcn_update_dpp(
        __builtin_bit_cast(int, x), __builtin_bit_cast(int, x),
        CTRL, RMASK, 0xf, false));
}

// Wave64 sum/max -> lane 63, then broadcast.
__device__ __forceinline__ float dpp_sum_to63(float x) {
    x += dpp_mv<0x111, 0xf>(x);   // row_shr:1
    x += dpp_mv<0x112, 0xf>(x);   // row_shr:2
    x += dpp_mv<0x114, 0xf>(x);   // row_shr:4
    x += dpp_mv<0x118, 0xf>(x);   // row_shr:8
    x += dpp_mv<0x142, 0xa>(x);   // row_bcast15 -> rows 1,3
    x += dpp_mv<0x143, 0xc>(x);   // row_bcast31 -> rows 2,3
    return x;
}
__device__ __forceinline__ float dpp_max_to63(float x) {
    x = fmaxf(x, dpp_mv<0x111, 0xf>(x));
    x = fmaxf(x, dpp_mv<0x112, 0xf>(x));
    x = fmaxf(x, dpp_mv<0x114, 0xf>(x));
    x = fmaxf(x, dpp_mv<0x118, 0xf>(x));
    x = fmaxf(x, dpp_mv<0x142, 0xa>(x));
    x = fmaxf(x, dpp_mv<0x143, 0xc>(x));
    return x;
}
__device__ __forceinline__ float bcast63(float x) {
    return __builtin_bit_cast(float,
        __builtin_amdgcn_readlane(__builtin_bit_cast(int, x), 63));
}
__device__ __forceinline__ float fast_rcp(float x) {
    float r;
    asm("v_rcp_f32 %0, %1" : "=v"(r) : "v"(x));
    return r;
}

// Compare-exchange, descending (a keeps max).
__device__ __forceinline__ void ce(float& a, float& b) {
    const float hi = fmaxf(a, b);
    const float lo = fminf(a, b);
    a = hi; b = lo;
}
__device__ __forceinline__ void sort4(float& a, float& b, float& c, float& d) {
    ce(a, b); ce(c, d); ce(a, c); ce(b, d); ce(b, c);
}
// Top-4 of two desc-sorted 4-lists (pruned odd-even merge).
__device__ __forceinline__ void merge44_top4(
    float A0, float A1, float A2, float A3,
    float B0, float B1, float B2, float B3,
    float& R0, float& R1, float& R2, float& R3) {
    float e0 = A0, e1 = A2, e2 = B0, e3 = B2;
    ce(e0, e2); ce(e1, e3); ce(e1, e2);
    float o0 = A1, o1 = A3, o2 = B1, o3 = B3;
    ce(o0, o2); ce(o1, o3); ce(o1, o2);
    R0 = e0;
    float x = o0, y = e1;
    ce(x, y);
    R1 = x; R2 = y;
    R3 = fmaxf(o1, e2);
}

// 4KB row DMA into this wave's LDS slot (zero-VGPR staging).
__device__ __forceinline__ void prefetch_row(const float* __restrict__ z,
                                             int row, int lane,
                                             float* ldsbase) {
    const char* g = (const char*)(z + (size_t)row * ROW_D) + (size_t)lane * 16;
#pragma unroll
    for (int j = 0; j < 4; ++j) {
        __builtin_amdgcn_global_load_lds(
            (const __attribute__((address_space(1))) void*)(g + j * 1024),
            (__attribute__((address_space(3))) void*)(ldsbase + j * 256),
            16, 0, 0);
    }
}

// R6 solve: top-4 compaction + exact fallback. Returns tau.
__device__ __forceinline__ float solve_tau(const f4 (&v)[4]) {
    float g[4][4];
#pragma unroll
    for (int j = 0; j < 4; ++j) {
        g[j][0] = v[j].x; g[j][1] = v[j].y; g[j][2] = v[j].z; g[j][3] = v[j].w;
        sort4(g[j][0], g[j][1], g[j][2], g[j][3]);
    }
    float a0, a1, a2, a3, b0, b1, b2, b3, T0, T1, T2, T3;
    merge44_top4(g[0][0], g[0][1], g[0][2], g[0][3],
                 g[1][0], g[1][1], g[1][2], g[1][3], a0, a1, a2, a3);
    merge44_top4(g[2][0], g[2][1], g[2][2], g[2][3],
                 g[3][0], g[3][1], g[3][2], g[3][3], b0, b1, b2, b3);
    merge44_top4(a0, a1, a2, a3, b0, b1, b2, b3, T0, T1, T2, T3);

    const float m = bcast63(dpp_max_to63(T0));
    float t = m - 1.0f;

    if (__ballot(T3 > t) == 0ull) {
        // Elements outside any lane's top-4 are <= t0 <= t forever: exact.
#pragma unroll 1
        for (int it = 0; it < 16; ++it) {
            const float d0 = T0 - t, d1 = T1 - t, d2 = T2 - t, d3 = T3 - t;
            const float Sl = (fmaxf(d0, 0.0f) + fmaxf(d1, 0.0f)) +
                             (fmaxf(d2, 0.0f) + fmaxf(d3, 0.0f));
            int n = __popcll(__ballot(d0 > 0.0f));
            n += __popcll(__ballot(d1 > 0.0f));
            n += __popcll(__ballot(d2 > 0.0f));
            n += __popcll(__ballot(d3 > 0.0f));
            const float S = bcast63(dpp_sum_to63(Sl));
            const float step = (S - 1.0f) * fast_rcp((float)n);  // n >= 1
            t += step;
            if (step <= 1e-6f) break;   // wave-uniform exit
        }
    } else {
#pragma unroll 1
        for (int it = 0; it < 16; ++it) {
            float sj[4];
            int n = 0;
#pragma unroll
            for (int j = 0; j < 4; ++j) {
                const float d0 = v[j].x - t, d1 = v[j].y - t;
                const float d2 = v[j].z - t, d3 = v[j].w - t;
                sj[j] = (fmaxf(d0, 0.0f) + fmaxf(d1, 0.0f)) +
                        (fmaxf(d2, 0.0f) + fmaxf(d3, 0.0f));
                n += __popcll(__ballot(d0 > 0.0f));
                n += __popcll(__ballot(d1 > 0.0f));
                n += __popcll(__ballot(d2 > 0.0f));
                n += __popcll(__ballot(d3 > 0.0f));
            }
            const float S = bcast63(dpp_sum_to63((sj[0] + sj[1]) + (sj[2] + sj[3])));
            const float step = (S - 1.0f) * fast_rcp((float)n);
            t += step;
            if (step <= 1e-6f) break;
        }
    }
    return t;
}

__device__ __forceinline__ void store_row(const f4 (&v)[4], float t,
                                          float* __restrict__ out,
                                          int row, int lane) {
    f4* __restrict__ p = reinterpret_cast<f4*>(out + (size_t)row * ROW_D);
#pragma unroll
    for (int j = 0; j < 4; ++j) {
        f4 o;
        o.x = fmaxf(v[j].x - t, 0.0f);
        o.y = fmaxf(v[j].y - t, 0.0f);
        o.z = fmaxf(v[j].z - t, 0.0f);
        o.w = fmaxf(v[j].w - t, 0.0f);
        p[lane + 64 * j] = o;
    }
}

__global__ __launch_bounds__(256) void sparsemax_kernel(
    const float* __restrict__ z, float* __restrict__ out, int nrows) {
    const int lane = (int)(threadIdx.x & 63u);
    const int w    = (int)(threadIdx.x >> 6);
    int r = (int)(blockIdx.x << 2) + w;
    const int W = (int)(gridDim.x << 2);   // 2048 total waves
    if (r >= nrows) return;

    __shared__ float lds[4][2][ROW_D];     // per-wave double buffer, 32KB

    // Prologue: row r direct to registers; DMA row r+W into slot 0.
    f4 v[4];
    {
        const f4* __restrict__ zin = reinterpret_cast<const f4*>(z + (size_t)r * ROW_D);
#pragma unroll
        for (int j = 0; j < 4; ++j) v[j] = zin[lane + 64 * j];
    }
    int rn = r + W;
    int s = 0;
    if (rn < nrows) prefetch_row(z, rn, lane, &lds[w][0][0]);
    __builtin_amdgcn_sched_barrier(0);

    for (;;) {
        const float t = solve_tau(v);          // DMA(rn) + prev stores in flight
        const int rf = rn + W;
        if (rn < nrows && rf < nrows)
            prefetch_row(z, rf, lane, &lds[w][s ^ 1][0]);   // DMA before stores
        __builtin_amdgcn_sched_barrier(0);
        store_row(v, t, out, r, lane);
        if (rn >= nrows) break;

        // In-order vmcnt: oldest outstanding are [DMA rn (4), stores r-1 (4)],
        // newest are [DMA rf (4), stores r (4)]. vmcnt(8) drains exactly the
        // first two groups -- prefetch complete, our fresh stores still fly.
        asm volatile("s_waitcnt vmcnt(8)" ::: "memory");
        __builtin_amdgcn_sched_barrier(0);
        const f4* lsrc = reinterpret_cast<const f4*>(&lds[w][s][0]);
#pragma unroll
        for (int j = 0; j < 4; ++j) v[j] = lsrc[lane + 64 * j];

        r = rn; rn = rf; s ^= 1;
    }
}

extern "C" void kernel_launch(void* const* d_in, const int* in_sizes, int n_in,
                              void* d_out, int out_size, void* d_ws, size_t ws_size,
                              hipStream_t stream) {
    const float* z = (const float*)d_in[0];
    float* out = (float*)d_out;
    const int n = in_sizes[0];            // 8*4096*1024
    const int nrows = n / ROW_D;          // 32768
    // Low-concurrency persistent grid: 512 blocks x 4 waves = 2048 waves
    // (2 blocks/CU, ~6% occupancy), 16 rows per wave.
    int blocks = 512;
    const int max_blocks = (nrows + 3) >> 2;
    if (blocks > max_blocks) blocks = max_blocks;
    sparsemax_kernel<<<blocks, 256, 0, stream>>>(z, out, nrows);
}